// Round 2
// baseline (203.660 us; speedup 1.0000x reference)
//
#include <hip/hip_runtime.h>

// ShiftAwareAttention1D — algebraic collapse.
//
// grid_sample input has W=1; offsets feed the x coord: x=(g+1)*0.5*(W-1)=0
// always. y coord is constant 0 -> y=(L-1)/2=1023.5, so every (l,p) samples
// 0.5*(v[...,1023]+v[...,1024]); softmax weights sum to 1 (no-op). The op is:
//   u[b]     = 0.5*(value[b,1023,:]+value[b,1024,:])
//   vproj[b] = Wv @ u[b] + bv            (GEMV 1024x1024, x8 batches)
//   orow[b]  = Wout @ vproj[b] + bout    (GEMV 1024x1024, x8 batches)
//   out[b,l,:] = orow[b,:]               (broadcast, 64 MiB write = roofline)

#define BB 8
#define LL 2048
#define DD 1024

typedef float f32x4 __attribute__((ext_vector_type(4)));

// ---------------------------------------------------------------------------
// Kernel 1: vproj[b][d] = Wv[d,:] . 0.5*(value[b,1023,:]+value[b,1024,:]) + bv[d]
// One wave per output row d; 8 batch accumulators; butterfly reduce.
// ---------------------------------------------------------------------------
__global__ __launch_bounds__(64) void k_vproj(const float* __restrict__ value,
                                              const float* __restrict__ Wv,
                                              const float* __restrict__ bv,
                                              float* __restrict__ vproj) {
    const int d = blockIdx.x;
    const int lane = threadIdx.x;
    const f32x4* W4 = (const f32x4*)(Wv + (size_t)d * DD);

    float acc[BB];
#pragma unroll
    for (int b = 0; b < BB; ++b) acc[b] = 0.f;

#pragma unroll
    for (int i = 0; i < 4; ++i) {
        const int k4 = lane + 64 * i;           // float4 index within the row
        const f32x4 w = W4[k4];
#pragma unroll
        for (int b = 0; b < BB; ++b) {
            const f32x4* p = (const f32x4*)(value + ((size_t)b * LL + 1023) * DD);
            const f32x4 v0 = p[k4];             // row 1023
            const f32x4 v1 = p[k4 + DD / 4];    // row 1024
            const f32x4 u = 0.5f * (v0 + v1);
            acc[b] += w.x * u.x + w.y * u.y + w.z * u.z + w.w * u.w;
        }
    }

#pragma unroll
    for (int off = 32; off >= 1; off >>= 1) {
#pragma unroll
        for (int b = 0; b < BB; ++b) acc[b] += __shfl_xor(acc[b], off, 64);
    }

    if (lane == 0) {
        const float bias = bv[d];
#pragma unroll
        for (int b = 0; b < BB; ++b) vproj[(size_t)b * DD + d] = acc[b] + bias;
    }
}

// ---------------------------------------------------------------------------
// Kernel 2: orow[b][d] = Wout[d,:] . vproj[b,:] + bout[d]
// ---------------------------------------------------------------------------
__global__ __launch_bounds__(64) void k_orow(const float* __restrict__ vproj,
                                             const float* __restrict__ Wout,
                                             const float* __restrict__ bout,
                                             float* __restrict__ orow) {
    const int d = blockIdx.x;
    const int lane = threadIdx.x;
    const f32x4* W4 = (const f32x4*)(Wout + (size_t)d * DD);
    const f32x4* in4 = (const f32x4*)vproj;

    float acc[BB];
#pragma unroll
    for (int b = 0; b < BB; ++b) acc[b] = 0.f;

#pragma unroll
    for (int i = 0; i < 4; ++i) {
        const int k4 = lane + 64 * i;
        const f32x4 w = W4[k4];
#pragma unroll
        for (int b = 0; b < BB; ++b) {
            const f32x4 v = in4[b * (DD / 4) + k4];
            acc[b] += w.x * v.x + w.y * v.y + w.z * v.z + w.w * v.w;
        }
    }

#pragma unroll
    for (int off = 32; off >= 1; off >>= 1) {
#pragma unroll
        for (int b = 0; b < BB; ++b) acc[b] += __shfl_xor(acc[b], off, 64);
    }

    if (lane == 0) {
        const float bias = bout[d];
#pragma unroll
        for (int b = 0; b < BB; ++b) orow[(size_t)b * DD + d] = acc[b] + bias;
    }
}

// ---------------------------------------------------------------------------
// Kernel 3: out[b][l][:] = orow[b][:]   — 64 MiB HBM write, the roofline term.
// Block = (b, chunk of 8 l's); lane owns one d4 (f32x4). The orow value is
// loaded ONCE into a register; the inner loop is pure contiguous nontemporal
// stores (4 KiB per block per l) — same pattern as the 6.6 TB/s fill kernel.
// ---------------------------------------------------------------------------
__global__ __launch_bounds__(256) void k_bcast(const float* __restrict__ orow,
                                               float* __restrict__ out) {
    const int b = blockIdx.x >> 8;            // 0..7
    const int lchunk = blockIdx.x & 255;      // 0..255, 8 l's each
    const int d4 = threadIdx.x;               // 0..255 (f32x4 index in D)
    const f32x4 o = ((const f32x4*)orow)[b * (DD / 4) + d4];
    f32x4* dst = (f32x4*)out + ((size_t)b * LL + (size_t)lchunk * 8) * (DD / 4) + d4;
#pragma unroll
    for (int j = 0; j < 8; ++j)
        __builtin_nontemporal_store(o, dst + (size_t)j * (DD / 4));
}

extern "C" void kernel_launch(void* const* d_in, const int* in_sizes, int n_in,
                              void* d_out, int out_size, void* d_ws, size_t ws_size,
                              hipStream_t stream) {
    // setup_inputs order: query, key_in, value, Wv, bv, Woff, boff, Ww, bw, Wout, bout
    const float* value = (const float*)d_in[2];
    const float* Wv    = (const float*)d_in[3];
    const float* bv    = (const float*)d_in[4];
    const float* Wout  = (const float*)d_in[9];
    const float* bout  = (const float*)d_in[10];
    float* out = (float*)d_out;

    float* vproj = (float*)d_ws;          // B*D floats = 32 KiB
    float* orow  = vproj + BB * DD;       // B*D floats = 32 KiB

    k_vproj<<<DD, 64, 0, stream>>>(value, Wv, bv, vproj);
    k_orow <<<DD, 64, 0, stream>>>(vproj, Wout, bout, orow);
    k_bcast<<<BB * 256, 256, 0, stream>>>(orow, out);
}